// Round 1
// baseline (990.205 us; speedup 1.0000x reference)
//
#include <hip/hip_runtime.h>
#include <stdint.h>

// Problem constants
#define T_ 4
#define B_ 16
#define N_ 197
#define D_ 512
#define H_ 8
#define DH 64
#define BN_ (B_*N_)              // 3152 rows per timestep
#define PLANE (BN_*D_)           // 1,613,824 elems per t-plane
#define M_ (T_*BN_)              // 12608 GEMM rows (divisible by 64)
#define TENSOR_ELEMS (T_*PLANE)  // 6,455,296 elems per (T,B,N,D) tensor
#define FLAG_TOL 1e-4f           // ~250x max expected f32 GEMM error
#define MAXFLAG 65536

// ---------------------------------------------------------------------------
// f32 tiled GEMM: C[M,512] = A[M,512] @ W[512,512]^T (+bias), W row-major [e][d]
// 64x64 tile, BK=32, 256 threads, 4x4 micro-tile. M=12608, N=512 exact tiles.
// ---------------------------------------------------------------------------
#define BM 64
#define BNT 64
#define BK 32

__global__ __launch_bounds__(256)
void gemm_f32(const float* __restrict__ A, const float* __restrict__ W,
              const float* __restrict__ bias, float* __restrict__ C)
{
    __shared__ __align__(16) float As[BK][BM+4];
    __shared__ __align__(16) float Ws[BK][BNT+4];
    const int tid = threadIdx.x;
    const int tx = tid & 15, ty = tid >> 4;
    const float* Ab = A + (size_t)blockIdx.x*BM*D_;
    const float* Wb = W + (size_t)blockIdx.y*BNT*D_;
    float acc[4][4] = {};
    for (int kt = 0; kt < D_; kt += BK) {
        #pragma unroll
        for (int i = 0; i < 2; ++i) {
            int vid = tid + i*256;
            int row = vid >> 3, c4 = (vid & 7)*4;
            float4 av = *(const float4*)(Ab + (size_t)row*D_ + kt + c4);
            float4 wv = *(const float4*)(Wb + (size_t)row*D_ + kt + c4);
            As[c4+0][row]=av.x; As[c4+1][row]=av.y; As[c4+2][row]=av.z; As[c4+3][row]=av.w;
            Ws[c4+0][row]=wv.x; Ws[c4+1][row]=wv.y; Ws[c4+2][row]=wv.z; Ws[c4+3][row]=wv.w;
        }
        __syncthreads();
        #pragma unroll
        for (int kk = 0; kk < BK; ++kk) {
            float4 a4 = *(const float4*)&As[kk][ty*4];
            float4 b4 = *(const float4*)&Ws[kk][tx*4];
            float ar[4] = {a4.x, a4.y, a4.z, a4.w};
            float br[4] = {b4.x, b4.y, b4.z, b4.w};
            #pragma unroll
            for (int i = 0; i < 4; ++i)
                #pragma unroll
                for (int j = 0; j < 4; ++j)
                    acc[i][j] += ar[i]*br[j];
        }
        __syncthreads();
    }
    const int row0 = blockIdx.x*BM + ty*4;
    const int col0 = blockIdx.y*BNT + tx*4;
    #pragma unroll
    for (int i = 0; i < 4; ++i)
        #pragma unroll
        for (int j = 0; j < 4; ++j) {
            float cv = acc[i][j];
            if (bias) cv += bias[col0+j];
            C[(size_t)(row0+i)*D_ + col0 + j] = cv;
        }
}

// ---------------------------------------------------------------------------
// LIF over T=4 for q,k,v in place (pre-spike values -> binary spikes as f32).
// Flags chains whose membrane potential passes within FLAG_TOL of threshold
// at any step (those get an exact f64 recompute).
// ---------------------------------------------------------------------------
__global__ void lif3_flag(float* qkv, unsigned int* cnt, unsigned int* list)
{
    int idx = blockIdx.x*256 + threadIdx.x;        // [0, 3*PLANE)
    int tsr = idx / PLANE;
    int rem = idx - tsr*PLANE;
    float* buf = qkv + (size_t)tsr*TENSOR_ELEMS;
    float v = 0.f; bool flag = false;
    #pragma unroll
    for (int t = 0; t < T_; ++t) {
        float x = buf[(size_t)t*PLANE + rem];
        float h = v + (x - v)*0.5f;                // h = v + (x-v)/TAU, TAU=2
        bool s = h >= 1.0f;
        flag |= fabsf(h - 1.0f) < FLAG_TOL;
        buf[(size_t)t*PLANE + rem] = s ? 1.0f : 0.0f;
        v = s ? 0.0f : h;
    }
    if (flag) {
        unsigned int p = atomicAdd(cnt, 1u);
        if (p < MAXFLAG) list[p] = (unsigned int)idx;
    }
}

// f64 exact recompute of flagged (tensor, row, col) chains for q/k/v.
__global__ void fixup_qkv(const float* __restrict__ x,
                          const float* __restrict__ Wq, const float* __restrict__ Wk,
                          const float* __restrict__ Wv,
                          float* qkv, const unsigned int* cnt, const unsigned int* list)
{
    unsigned int n = *cnt; if (n > MAXFLAG) n = MAXFLAG;
    int lane = threadIdx.x;                        // 64 threads = 1 wave
    for (unsigned int ii = blockIdx.x; ii < n; ii += gridDim.x) {
        unsigned int id = list[ii];
        int tsr = id / PLANE;
        int rem = id - tsr*PLANE;
        int r = rem >> 9, e = rem & (D_-1);
        const float* W = (tsr==0) ? Wq : (tsr==1 ? Wk : Wv);
        float* buf = qkv + (size_t)tsr*TENSOR_ELEMS;
        double dots[T_];
        #pragma unroll
        for (int t = 0; t < T_; ++t) {
            const float* xr = x + (size_t)(t*BN_ + r)*D_;
            const float* wr = W + (size_t)e*D_;
            double p = 0.0;
            for (int d = lane; d < D_; d += 64)
                p += (double)xr[d] * (double)wr[d];
            #pragma unroll
            for (int off = 32; off > 0; off >>= 1)
                p += __shfl_down(p, off);
            dots[t] = p;
        }
        if (lane == 0) {
            double v = 0.0;
            #pragma unroll
            for (int t = 0; t < T_; ++t) {
                double h = v + (dots[t] - v)/2.0;
                bool s = h >= 1.0;
                buf[(size_t)t*PLANE + rem] = s ? 1.0f : 0.0f;
                v = s ? 0.0 : h;
            }
        }
    }
}

// ---------------------------------------------------------------------------
// Binary attention: per (t,b,h) block. Spikes packed to 64-bit masks (dh=64).
// attn[i][j] = popcount(Qb[i]&Kb[j])/8  (exact); out = attn @ vs (exact).
// ---------------------------------------------------------------------------
__global__ __launch_bounds__(256)
void attn_kernel(const float* __restrict__ qb, const float* __restrict__ kb,
                 const float* __restrict__ vb,
                 float* __restrict__ attn_out, float* __restrict__ obuf)
{
    int tb = blockIdx.x;                           // t*B + b in [0,64)
    int h  = blockIdx.y;                           // [0,8)
    __shared__ unsigned long long Qb[N_], Kb[N_], Vb[N_];
    int wave = threadIdx.x >> 6, lane = threadIdx.x & 63;

    // pack spikes into bitmasks via ballot (lane = d)
    for (int j = wave; j < N_; j += 4) {
        size_t base = ((size_t)tb*N_ + j)*D_ + h*DH + lane;
        unsigned long long mq = __ballot(qb[base] != 0.f);
        unsigned long long mk = __ballot(kb[base] != 0.f);
        unsigned long long mv = __ballot(vb[base] != 0.f);
        if (lane == 0) { Qb[j] = mq; Kb[j] = mk; Vb[j] = mv; }
    }
    __syncthreads();

    // attn_map writes (coalesced, lane = j)
    size_t amap_base = ((size_t)tb*H_ + h)*N_*N_;
    for (int i = wave; i < N_; i += 4) {
        unsigned long long qi = Qb[i];
        #pragma unroll
        for (int c = 0; c < 4; ++c) {
            int j = c*64 + lane;
            if (j < N_) {
                int s = __popcll(qi & Kb[j]);
                attn_out[amap_base + (size_t)i*N_ + j] = s*0.125f;
            }
        }
    }

    // out[i][d] = (sum_j popcount(Qb[i]&Kb[j]) * V[j][d]) / 8  (lane = d)
    for (int i = wave; i < N_; i += 4) {
        unsigned long long qi = Qb[i];
        int acc = 0;
        #pragma unroll 4
        for (int j = 0; j < N_; ++j) {
            int s = __popcll(qi & Kb[j]);
            acc += (int)((Vb[j] >> lane) & 1ull) * s;
        }
        obuf[((size_t)tb*N_ + i)*D_ + h*DH + lane] = acc*0.125f;
    }
}

// ---------------------------------------------------------------------------
// Final LIF (proj -> output spikes) with flagging, and its f64 fixup.
// ---------------------------------------------------------------------------
__global__ void lif_proj(const float* __restrict__ proj, float* __restrict__ outp,
                         unsigned int* cnt, unsigned int* list)
{
    int idx = blockIdx.x*256 + threadIdx.x;        // [0, PLANE)
    float v = 0.f; bool flag = false;
    #pragma unroll
    for (int t = 0; t < T_; ++t) {
        float xv = proj[(size_t)t*PLANE + idx];
        float h = v + (xv - v)*0.5f;
        bool s = h >= 1.0f;
        flag |= fabsf(h - 1.0f) < FLAG_TOL;
        outp[(size_t)t*PLANE + idx] = s ? 1.0f : 0.0f;
        v = s ? 0.0f : h;
    }
    if (flag) {
        unsigned int p = atomicAdd(cnt, 1u);
        if (p < MAXFLAG) list[p] = (unsigned int)idx;
    }
}

__global__ void fixup_proj(const float* __restrict__ obuf, const float* __restrict__ Wp,
                           const float* __restrict__ bp, float* __restrict__ outp,
                           const unsigned int* cnt, const unsigned int* list)
{
    unsigned int n = *cnt; if (n > MAXFLAG) n = MAXFLAG;
    int lane = threadIdx.x;
    for (unsigned int ii = blockIdx.x; ii < n; ii += gridDim.x) {
        unsigned int rem = list[ii];
        int r = rem >> 9, e = rem & (D_-1);
        double dots[T_];
        #pragma unroll
        for (int t = 0; t < T_; ++t) {
            const float* ar = obuf + (size_t)(t*BN_ + r)*D_;
            const float* wr = Wp + (size_t)e*D_;
            double p = 0.0;
            for (int d = lane; d < D_; d += 64)
                p += (double)ar[d] * (double)wr[d];
            #pragma unroll
            for (int off = 32; off > 0; off >>= 1)
                p += __shfl_down(p, off);
            dots[t] = p;
        }
        if (lane == 0) {
            double v = 0.0;
            #pragma unroll
            for (int t = 0; t < T_; ++t) {
                double xt = dots[t] + (double)bp[e];
                double h = v + (xt - v)/2.0;
                bool s = h >= 1.0;
                outp[(size_t)t*PLANE + rem] = s ? 1.0f : 0.0f;
                v = s ? 0.0 : h;
            }
        }
    }
}

// ---------------------------------------------------------------------------
extern "C" void kernel_launch(void* const* d_in, const int* in_sizes, int n_in,
                              void* d_out, int out_size, void* d_ws, size_t ws_size,
                              hipStream_t stream)
{
    const float* x  = (const float*)d_in[0];
    const float* Wq = (const float*)d_in[1];
    const float* Wk = (const float*)d_in[2];
    const float* Wv = (const float*)d_in[3];
    const float* Wp = (const float*)d_in[4];
    const float* bp = (const float*)d_in[5];
    float* out_spk  = (float*)d_out;                       // (T,B,N,D) spikes
    float* attn_out = (float*)d_out + TENSOR_ELEMS;        // (T,B,H,N,N)

    char* ws = (char*)d_ws;
    const size_t BUFB = (size_t)TENSOR_ELEMS * sizeof(float);
    float* qkv  = (float*)ws;                              // q,k,v (3 tensors)
    float* obuf = (float*)(ws + 3*BUFB);                   // attention output
    float* pbuf = qkv;                                     // proj result reuses q region
    unsigned int* cnt0  = (unsigned int*)(ws + 4*BUFB);
    unsigned int* cnt1  = cnt0 + 1;
    unsigned int* list0 = cnt0 + 2;
    unsigned int* list1 = list0 + MAXFLAG;
    if (ws_size < 4*BUFB + 8 + 2*(size_t)MAXFLAG*4) return;

    hipMemsetAsync(cnt0, 0, 8, stream);

    dim3 gg(M_/BM, D_/BNT);
    // QKV projections (f32)
    gemm_f32<<<gg, 256, 0, stream>>>(x, Wq, nullptr, qkv);
    gemm_f32<<<gg, 256, 0, stream>>>(x, Wk, nullptr, qkv + TENSOR_ELEMS);
    gemm_f32<<<gg, 256, 0, stream>>>(x, Wv, nullptr, qkv + 2*(size_t)TENSOR_ELEMS);
    // LIF + boundary flags, then exact f64 fixup of flagged chains
    lif3_flag<<<3*PLANE/256, 256, 0, stream>>>(qkv, cnt0, list0);
    fixup_qkv<<<1024, 64, 0, stream>>>(x, Wq, Wk, Wv, qkv, cnt0, list0);
    // binary attention (exact integer math)
    attn_kernel<<<dim3(T_*B_, H_), 256, 0, stream>>>(
        qkv, qkv + TENSOR_ELEMS, qkv + 2*(size_t)TENSOR_ELEMS, attn_out, obuf);
    // output projection + bias (f32), LIF + flags, f64 fixup
    gemm_f32<<<gg, 256, 0, stream>>>(obuf, Wp, bp, pbuf);
    lif_proj<<<PLANE/256, 256, 0, stream>>>(pbuf, out_spk, cnt1, list1);
    fixup_proj<<<1024, 64, 0, stream>>>(obuf, Wp, bp, out_spk, cnt1, list1);
}

// Round 2
// 574.974 us; speedup vs baseline: 1.7222x; 1.7222x over previous
//
#include <hip/hip_runtime.h>
#include <stdint.h>

// Problem constants
#define T_ 4
#define B_ 16
#define N_ 197
#define D_ 512
#define H_ 8
#define DH 64
#define BN_ (B_*N_)              // 3152 rows per timestep
#define PLANE (BN_*D_)           // 1,613,824 elems per t-plane
#define M_ (T_*BN_)              // 12608 GEMM rows (divisible by 64)
#define TENSOR_ELEMS (T_*PLANE)  // 6,455,296 elems per (T,B,N,D) tensor
#define FLAG_TOL 1e-4f           // ~250x max expected f32 GEMM error
#define MAXFLAG 65536

typedef __attribute__((ext_vector_type(8))) short short8v;
typedef __attribute__((ext_vector_type(4))) float f32x4;

// ---------------------------------------------------------------------------
// f32 tiled GEMM: C[M,512] = A[M,512] @ W[512,512]^T (+bias), W row-major [e][d]
// ---------------------------------------------------------------------------
#define BM 64
#define BNT 64
#define BK 32

__global__ __launch_bounds__(256)
void gemm_f32(const float* __restrict__ A, const float* __restrict__ W,
              const float* __restrict__ bias, float* __restrict__ C)
{
    __shared__ __align__(16) float As[BK][BM+4];
    __shared__ __align__(16) float Ws[BK][BNT+4];
    const int tid = threadIdx.x;
    const int tx = tid & 15, ty = tid >> 4;
    const float* Ab = A + (size_t)blockIdx.x*BM*D_;
    const float* Wb = W + (size_t)blockIdx.y*BNT*D_;
    float acc[4][4] = {};
    for (int kt = 0; kt < D_; kt += BK) {
        #pragma unroll
        for (int i = 0; i < 2; ++i) {
            int vid = tid + i*256;
            int row = vid >> 3, c4 = (vid & 7)*4;
            float4 av = *(const float4*)(Ab + (size_t)row*D_ + kt + c4);
            float4 wv = *(const float4*)(Wb + (size_t)row*D_ + kt + c4);
            As[c4+0][row]=av.x; As[c4+1][row]=av.y; As[c4+2][row]=av.z; As[c4+3][row]=av.w;
            Ws[c4+0][row]=wv.x; Ws[c4+1][row]=wv.y; Ws[c4+2][row]=wv.z; Ws[c4+3][row]=wv.w;
        }
        __syncthreads();
        #pragma unroll
        for (int kk = 0; kk < BK; ++kk) {
            float4 a4 = *(const float4*)&As[kk][ty*4];
            float4 b4 = *(const float4*)&Ws[kk][tx*4];
            float ar[4] = {a4.x, a4.y, a4.z, a4.w};
            float br[4] = {b4.x, b4.y, b4.z, b4.w};
            #pragma unroll
            for (int i = 0; i < 4; ++i)
                #pragma unroll
                for (int j = 0; j < 4; ++j)
                    acc[i][j] += ar[i]*br[j];
        }
        __syncthreads();
    }
    const int row0 = blockIdx.x*BM + ty*4;
    const int col0 = blockIdx.y*BNT + tx*4;
    #pragma unroll
    for (int i = 0; i < 4; ++i)
        #pragma unroll
        for (int j = 0; j < 4; ++j) {
            float cv = acc[i][j];
            if (bias) cv += bias[col0+j];
            C[(size_t)(row0+i)*D_ + col0 + j] = cv;
        }
}

// ---------------------------------------------------------------------------
// LIF over T=4 for q,k,v in place; flags near-threshold chains for f64 fixup.
// ---------------------------------------------------------------------------
__global__ void lif3_flag(float* qkv, unsigned int* cnt, unsigned int* list)
{
    int idx = blockIdx.x*256 + threadIdx.x;        // [0, 3*PLANE)
    int tsr = idx / PLANE;
    int rem = idx - tsr*PLANE;
    float* buf = qkv + (size_t)tsr*TENSOR_ELEMS;
    float v = 0.f; bool flag = false;
    #pragma unroll
    for (int t = 0; t < T_; ++t) {
        float x = buf[(size_t)t*PLANE + rem];
        float h = v + (x - v)*0.5f;
        bool s = h >= 1.0f;
        flag |= fabsf(h - 1.0f) < FLAG_TOL;
        buf[(size_t)t*PLANE + rem] = s ? 1.0f : 0.0f;
        v = s ? 0.0f : h;
    }
    if (flag) {
        unsigned int p = atomicAdd(cnt, 1u);
        if (p < MAXFLAG) list[p] = (unsigned int)idx;
    }
}

__global__ void fixup_qkv(const float* __restrict__ x,
                          const float* __restrict__ Wq, const float* __restrict__ Wk,
                          const float* __restrict__ Wv,
                          float* qkv, const unsigned int* cnt, const unsigned int* list)
{
    unsigned int n = *cnt; if (n > MAXFLAG) n = MAXFLAG;
    int lane = threadIdx.x;                        // 64 threads = 1 wave
    for (unsigned int ii = blockIdx.x; ii < n; ii += gridDim.x) {
        unsigned int id = list[ii];
        int tsr = id / PLANE;
        int rem = id - tsr*PLANE;
        int r = rem >> 9, e = rem & (D_-1);
        const float* W = (tsr==0) ? Wq : (tsr==1 ? Wk : Wv);
        float* buf = qkv + (size_t)tsr*TENSOR_ELEMS;
        double dots[T_];
        #pragma unroll
        for (int t = 0; t < T_; ++t) {
            const float* xr = x + (size_t)(t*BN_ + r)*D_;
            const float* wr = W + (size_t)e*D_;
            double p = 0.0;
            for (int d = lane; d < D_; d += 64)
                p += (double)xr[d] * (double)wr[d];
            #pragma unroll
            for (int off = 32; off > 0; off >>= 1)
                p += __shfl_down(p, off);
            dots[t] = p;
        }
        if (lane == 0) {
            double v = 0.0;
            #pragma unroll
            for (int t = 0; t < T_; ++t) {
                double h = v + (dots[t] - v)/2.0;
                bool s = h >= 1.0;
                buf[(size_t)t*PLANE + rem] = s ? 1.0f : 0.0f;
                v = s ? 0.0 : h;
            }
        }
    }
}

// ---------------------------------------------------------------------------
// MFMA attention. Exact math: spikes are 0/1 bf16; QK counts accumulate
// exactly in f32; attn = k/8 (k<256) exact in bf16; PV sums are multiples
// of 1/8 below 2^24 -> exact in f32 accumulation.
// ---------------------------------------------------------------------------
#define NP 208   // 13 * 16 (padded N)
#define LSTR 72  // LDS row stride (ushorts) for Q/K tiles: 144B -> 2-way banks
#define JP 224   // 7 * 32 (padded j for PV K-dim)
#define VSTR 232 // LDS row stride for Vt / S strips: 464B -> 2-way banks

// S = Q @ K^T, scaled 0.125, written to attn_out (T,B,H,N,N) f32.
__global__ __launch_bounds__(256)
void attn_qk(const float* __restrict__ qb, const float* __restrict__ kb,
             float* __restrict__ attn_out)
{
    __shared__ ushort Qs[NP][LSTR];
    __shared__ ushort Ks[NP][LSTR];
    int tb = blockIdx.x, h = blockIdx.y;
    int tid = threadIdx.x, wave = tid >> 6, lane = tid & 63;

    // stage Q,K spikes (f32 0/1 -> bf16 0/0x3F80); rows >= N_ zeroed
    for (int idx = tid; idx < NP*16; idx += 256) {
        int j = idx >> 4, d4 = (idx & 15) << 2;
        ushort qv[4] = {0,0,0,0}, kv[4] = {0,0,0,0};
        if (j < N_) {
            size_t base = ((size_t)tb*N_ + j)*D_ + (size_t)h*DH + d4;
            float4 q4 = *(const float4*)(qb + base);
            float4 k4 = *(const float4*)(kb + base);
            qv[0] = q4.x!=0.f?0x3F80:0; qv[1] = q4.y!=0.f?0x3F80:0;
            qv[2] = q4.z!=0.f?0x3F80:0; qv[3] = q4.w!=0.f?0x3F80:0;
            kv[0] = k4.x!=0.f?0x3F80:0; kv[1] = k4.y!=0.f?0x3F80:0;
            kv[2] = k4.z!=0.f?0x3F80:0; kv[3] = k4.w!=0.f?0x3F80:0;
        }
        #pragma unroll
        for (int r = 0; r < 4; ++r) { Qs[j][d4+r] = qv[r]; Ks[j][d4+r] = kv[r]; }
    }
    __syncthreads();

    const int il = lane & 15;             // A-row / B-col within tile
    const int kk = (lane >> 4) << 3;      // K-offset (8 contiguous bf16)
    const int ig = (lane >> 4) << 2;      // C-frag row group
    const size_t amap = ((size_t)tb*H_ + h)*(size_t)(N_*N_);

    for (int it = wave; it < 13; it += 4) {
        int i0 = it << 4;
        short8v a0 = *(const short8v*)&Qs[i0 + il][kk];
        short8v a1 = *(const short8v*)&Qs[i0 + il][kk + 32];
        for (int jt = 0; jt < 13; ++jt) {
            int j0 = jt << 4;
            short8v b0 = *(const short8v*)&Ks[j0 + il][kk];
            short8v b1 = *(const short8v*)&Ks[j0 + il][kk + 32];
            f32x4 c = {0.f, 0.f, 0.f, 0.f};
            c = __builtin_amdgcn_mfma_f32_16x16x32_bf16(a0, b0, c, 0, 0, 0);
            c = __builtin_amdgcn_mfma_f32_16x16x32_bf16(a1, b1, c, 0, 0, 0);
            int j = j0 + il;              // C col = lane&15
            if (j < N_) {
                #pragma unroll
                for (int r = 0; r < 4; ++r) {
                    int i = i0 + ig + r;  // C row = (lane>>4)*4 + r
                    if (i < N_) attn_out[amap + (size_t)i*N_ + j] = c[r]*0.125f;
                }
            }
        }
    }
}

// O = attn @ V. attn read back f32 -> bf16 (exact truncation), V transposed
// in LDS so B-fragments read 8 contiguous j.
__global__ __launch_bounds__(256)
void attn_pv(const float* __restrict__ attn, const float* __restrict__ vb,
             float* __restrict__ obuf)
{
    __shared__ ushort Vt[DH][VSTR];
    __shared__ ushort Ss[4][16][VSTR];
    int tb = blockIdx.x, h = blockIdx.y;
    int tid = threadIdx.x, wave = tid >> 6, lane = tid & 63;

    // stage V transposed: Vt[d][j], j >= N_ zeroed
    for (int idx = tid; idx < JP*16; idx += 256) {
        int j = idx >> 4, d4 = (idx & 15) << 2;
        ushort vv[4] = {0,0,0,0};
        if (j < N_) {
            size_t base = ((size_t)tb*N_ + j)*D_ + (size_t)h*DH + d4;
            float4 v4 = *(const float4*)(vb + base);
            vv[0] = v4.x!=0.f?0x3F80:0; vv[1] = v4.y!=0.f?0x3F80:0;
            vv[2] = v4.z!=0.f?0x3F80:0; vv[3] = v4.w!=0.f?0x3F80:0;
        }
        Vt[d4+0][j]=vv[0]; Vt[d4+1][j]=vv[1]; Vt[d4+2][j]=vv[2]; Vt[d4+3][j]=vv[3];
    }
    // zero this wave's strip pad cols [208, 224)
    for (int idx = lane; idx < 16*16; idx += 64)
        Ss[wave][idx >> 4][208 + (idx & 15)] = 0;
    __syncthreads();

    const int il = lane & 15, kk = (lane >> 4) << 3, ig = (lane >> 4) << 2;
    const size_t amap = ((size_t)tb*H_ + h)*(size_t)(N_*N_);

    for (int it = wave; it < 13; it += 4) {
        int i0 = it << 4;
        // load S strip rows i0..i0+15, cols 0..207 (f32 -> bf16 truncation)
        #pragma unroll 4
        for (int r = 0; r < 16; ++r) {
            int i = i0 + r;
            bool live = i < N_;
            const float* arow = attn + amap + (size_t)i*N_;
            for (int c = lane; c < NP; c += 64) {
                float av = (live && c < N_) ? arow[c] : 0.f;
                Ss[wave][r][c] = (ushort)(__float_as_uint(av) >> 16);
            }
        }
        #pragma unroll
        for (int dt = 0; dt < 4; ++dt) {
            f32x4 o = {0.f, 0.f, 0.f, 0.f};
            #pragma unroll
            for (int kt = 0; kt < 7; ++kt) {
                short8v a = *(const short8v*)&Ss[wave][il][kt*32 + kk];
                short8v b = *(const short8v*)&Vt[dt*16 + il][kt*32 + kk];
                o = __builtin_amdgcn_mfma_f32_16x16x32_bf16(a, b, o, 0, 0, 0);
            }
            #pragma unroll
            for (int r = 0; r < 4; ++r) {
                int i = i0 + ig + r;
                if (i < N_)
                    obuf[((size_t)tb*N_ + i)*D_ + (size_t)h*DH + dt*16 + il] = o[r];
            }
        }
    }
}

// ---------------------------------------------------------------------------
// Final LIF (proj -> output spikes) with flagging, and its f64 fixup.
// ---------------------------------------------------------------------------
__global__ void lif_proj(const float* __restrict__ proj, float* __restrict__ outp,
                         unsigned int* cnt, unsigned int* list)
{
    int idx = blockIdx.x*256 + threadIdx.x;        // [0, PLANE)
    float v = 0.f; bool flag = false;
    #pragma unroll
    for (int t = 0; t < T_; ++t) {
        float xv = proj[(size_t)t*PLANE + idx];
        float h = v + (xv - v)*0.5f;
        bool s = h >= 1.0f;
        flag |= fabsf(h - 1.0f) < FLAG_TOL;
        outp[(size_t)t*PLANE + idx] = s ? 1.0f : 0.0f;
        v = s ? 0.0f : h;
    }
    if (flag) {
        unsigned int p = atomicAdd(cnt, 1u);
        if (p < MAXFLAG) list[p] = (unsigned int)idx;
    }
}

__global__ void fixup_proj(const float* __restrict__ obuf, const float* __restrict__ Wp,
                           const float* __restrict__ bp, float* __restrict__ outp,
                           const unsigned int* cnt, const unsigned int* list)
{
    unsigned int n = *cnt; if (n > MAXFLAG) n = MAXFLAG;
    int lane = threadIdx.x;
    for (unsigned int ii = blockIdx.x; ii < n; ii += gridDim.x) {
        unsigned int rem = list[ii];
        int r = rem >> 9, e = rem & (D_-1);
        double dots[T_];
        #pragma unroll
        for (int t = 0; t < T_; ++t) {
            const float* ar = obuf + (size_t)(t*BN_ + r)*D_;
            const float* wr = Wp + (size_t)e*D_;
            double p = 0.0;
            for (int d = lane; d < D_; d += 64)
                p += (double)ar[d] * (double)wr[d];
            #pragma unroll
            for (int off = 32; off > 0; off >>= 1)
                p += __shfl_down(p, off);
            dots[t] = p;
        }
        if (lane == 0) {
            double v = 0.0;
            #pragma unroll
            for (int t = 0; t < T_; ++t) {
                double xt = dots[t] + (double)bp[e];
                double h = v + (xt - v)/2.0;
                bool s = h >= 1.0;
                outp[(size_t)t*PLANE + rem] = s ? 1.0f : 0.0f;
                v = s ? 0.0 : h;
            }
        }
    }
}

// ---------------------------------------------------------------------------
extern "C" void kernel_launch(void* const* d_in, const int* in_sizes, int n_in,
                              void* d_out, int out_size, void* d_ws, size_t ws_size,
                              hipStream_t stream)
{
    const float* x  = (const float*)d_in[0];
    const float* Wq = (const float*)d_in[1];
    const float* Wk = (const float*)d_in[2];
    const float* Wv = (const float*)d_in[3];
    const float* Wp = (const float*)d_in[4];
    const float* bp = (const float*)d_in[5];
    float* out_spk  = (float*)d_out;                       // (T,B,N,D) spikes
    float* attn_out = (float*)d_out + TENSOR_ELEMS;        // (T,B,H,N,N)

    char* ws = (char*)d_ws;
    const size_t BUFB = (size_t)TENSOR_ELEMS * sizeof(float);
    float* qkv  = (float*)ws;                              // q,k,v (3 tensors)
    float* obuf = (float*)(ws + 3*BUFB);                   // attention output
    float* pbuf = qkv;                                     // proj result reuses q region
    unsigned int* cnt0  = (unsigned int*)(ws + 4*BUFB);
    unsigned int* cnt1  = cnt0 + 1;
    unsigned int* list0 = cnt0 + 2;
    unsigned int* list1 = list0 + MAXFLAG;
    if (ws_size < 4*BUFB + 8 + 2*(size_t)MAXFLAG*4) return;

    hipMemsetAsync(cnt0, 0, 8, stream);

    dim3 gg(M_/BM, D_/BNT);
    // QKV projections (f32)
    gemm_f32<<<gg, 256, 0, stream>>>(x, Wq, nullptr, qkv);
    gemm_f32<<<gg, 256, 0, stream>>>(x, Wk, nullptr, qkv + TENSOR_ELEMS);
    gemm_f32<<<gg, 256, 0, stream>>>(x, Wv, nullptr, qkv + 2*(size_t)TENSOR_ELEMS);
    // LIF + boundary flags, then exact f64 fixup of flagged chains
    lif3_flag<<<3*PLANE/256, 256, 0, stream>>>(qkv, cnt0, list0);
    fixup_qkv<<<1024, 64, 0, stream>>>(x, Wq, Wk, Wv, qkv, cnt0, list0);
    // MFMA binary attention (exact)
    attn_qk<<<dim3(T_*B_, H_), 256, 0, stream>>>(
        qkv, qkv + TENSOR_ELEMS, attn_out);
    attn_pv<<<dim3(T_*B_, H_), 256, 0, stream>>>(
        attn_out, qkv + 2*(size_t)TENSOR_ELEMS, obuf);
    // output projection + bias (f32), LIF + flags, f64 fixup
    gemm_f32<<<gg, 256, 0, stream>>>(obuf, Wp, bp, pbuf);
    lif_proj<<<PLANE/256, 256, 0, stream>>>(pbuf, out_spk, cnt1, list1);
    fixup_proj<<<1024, 64, 0, stream>>>(obuf, Wp, bp, out_spk, cnt1, list1);
}

// Round 3
// 413.275 us; speedup vs baseline: 2.3960x; 1.3913x over previous
//
#include <hip/hip_runtime.h>
#include <stdint.h>

// Problem constants
#define T_ 4
#define B_ 16
#define N_ 197
#define D_ 512
#define H_ 8
#define DH 64
#define BN_ (B_*N_)              // 3152 rows per timestep
#define PLANE (BN_*D_)           // 1,613,824 elems per t-plane
#define M_ (T_*BN_)              // 12608 GEMM rows
#define TENSOR_ELEMS (T_*PLANE)  // 6,455,296 elems per (T,B,N,D) tensor
#define WELEMS (D_*D_)           // 262,144
#define FLAG_TOL 1e-3f           // >>100x worst-case split-GEMM dot error
#define MAXFLAG 65536

typedef __attribute__((ext_vector_type(8))) short short8v;
typedef __attribute__((ext_vector_type(4))) float f32x4;
typedef __attribute__((ext_vector_type(16))) float f32x16;
typedef __attribute__((ext_vector_type(4))) unsigned short ushort4v;

__device__ __forceinline__ ushort bf16_rne(float v) {
    uint u = __float_as_uint(v);
    return (ushort)((u + 0x7FFFu + ((u >> 16) & 1u)) >> 16);
}
__device__ __forceinline__ float bf16_f(ushort h) {
    return __uint_as_float(((uint)h) << 16);
}

// ---------------------------------------------------------------------------
// f32 -> bf16 hi/lo split (a = hi + lo + O(2^-18 a))
// ---------------------------------------------------------------------------
__global__ void split_kernel(const float* __restrict__ src, ushort* __restrict__ hi,
                             ushort* __restrict__ lo, int n)
{
    int i = (blockIdx.x*256 + threadIdx.x)*4;
    if (i >= n) return;
    float4 v = *(const float4*)(src + i);
    ushort4v hv, lv;
    float f[4] = {v.x, v.y, v.z, v.w};
    #pragma unroll
    for (int j = 0; j < 4; ++j) {
        ushort h = bf16_rne(f[j]);
        float rem = f[j] - bf16_f(h);
        hv[j] = h;
        lv[j] = bf16_rne(rem);
    }
    *(ushort4v*)(hi + i) = hv;
    *(ushort4v*)(lo + i) = lv;
}

// ---------------------------------------------------------------------------
// 3-pass split-bf16 MFMA GEMM: C[M,512] = A[M,512] @ W[512,512]^T (+bias)
// A,W given as bf16 hi/lo planes. 128x256 tile, 4 waves x (64x128),
// mfma_f32_32x32x16_bf16. blockIdx.z selects W plane / C plane (QKV fusion).
// ---------------------------------------------------------------------------
#define GBM 128
#define GBN 256
#define GBK 32
#define LSTR 40   // LDS row stride (ushorts), 80B: 16B-aligned, ~4-way banks

__global__ __launch_bounds__(256, 2)
void gemm_split(const ushort* __restrict__ Ahi, const ushort* __restrict__ Alo,
                const ushort* __restrict__ Whi, const ushort* __restrict__ Wlo,
                const float* __restrict__ bias, float* __restrict__ C,
                int wplane, long cplane)
{
    __shared__ ushort Ah[GBM][LSTR], Al[GBM][LSTR];
    __shared__ ushort Bh[GBN][LSTR], Bl[GBN][LSTR];
    const int tid = threadIdx.x;
    const int wave = tid >> 6, lane = tid & 63;
    const int wm = wave >> 1, wn = wave & 1;
    const int bm0 = blockIdx.x * GBM;
    const int bn0 = blockIdx.y * GBN;
    const int z = blockIdx.z;
    const ushort* Wh = Whi + (size_t)z * wplane;
    const ushort* Wl = Wlo + (size_t)z * wplane;
    float* Cz = C + (size_t)z * cplane;
    const int l31 = lane & 31;
    const int lg  = lane >> 5;

    f32x16 acc[2][4];
    #pragma unroll
    for (int fi = 0; fi < 2; ++fi)
        #pragma unroll
        for (int fj = 0; fj < 4; ++fj)
            #pragma unroll
            for (int r = 0; r < 16; ++r) acc[fi][fj][r] = 0.f;

    for (int kt = 0; kt < D_; kt += GBK) {
        __syncthreads();
        // stage A tile (128 x 32) hi/lo
        #pragma unroll
        for (int p = 0; p < 2; ++p) {
            int vid = tid + p*256;
            int r = vid >> 2, c = (vid & 3) * 8;
            int gr = bm0 + r;
            short8v h = {0,0,0,0,0,0,0,0}, l = {0,0,0,0,0,0,0,0};
            if (gr < M_) {
                h = *(const short8v*)(Ahi + (size_t)gr*D_ + kt + c);
                l = *(const short8v*)(Alo + (size_t)gr*D_ + kt + c);
            }
            *(short8v*)&Ah[r][c] = h;
            *(short8v*)&Al[r][c] = l;
        }
        // stage B tile (256 x 32) hi/lo
        #pragma unroll
        for (int p = 0; p < 4; ++p) {
            int vid = tid + p*256;
            int r = vid >> 2, c = (vid & 3) * 8;
            int gc = bn0 + r;
            short8v h = *(const short8v*)(Wh + (size_t)gc*D_ + kt + c);
            short8v l = *(const short8v*)(Wl + (size_t)gc*D_ + kt + c);
            *(short8v*)&Bh[r][c] = h;
            *(short8v*)&Bl[r][c] = l;
        }
        __syncthreads();
        #pragma unroll
        for (int s = 0; s < 2; ++s) {
            const int ko = s*16 + lg*8;
            short8v ah0 = *(const short8v*)&Ah[wm*64 +      l31][ko];
            short8v ah1 = *(const short8v*)&Ah[wm*64 + 32 + l31][ko];
            short8v al0 = *(const short8v*)&Al[wm*64 +      l31][ko];
            short8v al1 = *(const short8v*)&Al[wm*64 + 32 + l31][ko];
            #pragma unroll
            for (int fj = 0; fj < 4; ++fj) {
                short8v bh = *(const short8v*)&Bh[wn*128 + fj*32 + l31][ko];
                short8v bl = *(const short8v*)&Bl[wn*128 + fj*32 + l31][ko];
                acc[0][fj] = __builtin_amdgcn_mfma_f32_32x32x16_bf16(ah0, bh, acc[0][fj], 0, 0, 0);
                acc[0][fj] = __builtin_amdgcn_mfma_f32_32x32x16_bf16(ah0, bl, acc[0][fj], 0, 0, 0);
                acc[0][fj] = __builtin_amdgcn_mfma_f32_32x32x16_bf16(al0, bh, acc[0][fj], 0, 0, 0);
                acc[1][fj] = __builtin_amdgcn_mfma_f32_32x32x16_bf16(ah1, bh, acc[1][fj], 0, 0, 0);
                acc[1][fj] = __builtin_amdgcn_mfma_f32_32x32x16_bf16(ah1, bl, acc[1][fj], 0, 0, 0);
                acc[1][fj] = __builtin_amdgcn_mfma_f32_32x32x16_bf16(al1, bh, acc[1][fj], 0, 0, 0);
            }
        }
    }
    // epilogue: C/D layout col=lane&31, row=(reg&3)+8*(reg>>2)+4*(lane>>5)
    #pragma unroll
    for (int fi = 0; fi < 2; ++fi)
        #pragma unroll
        for (int fj = 0; fj < 4; ++fj) {
            int gcol = bn0 + wn*128 + fj*32 + l31;
            float bv = bias ? bias[gcol] : 0.f;
            #pragma unroll
            for (int r = 0; r < 16; ++r) {
                int grow = bm0 + wm*64 + fi*32 + (r&3) + 8*(r>>2) + 4*lg;
                if (grow < M_)
                    Cz[(size_t)grow*D_ + gcol] = acc[fi][fj][r] + bv;
            }
        }
}

// ---------------------------------------------------------------------------
// LIF over T=4 for q,k,v in place; flags near-threshold chains for f64 fixup.
// ---------------------------------------------------------------------------
__global__ void lif3_flag(float* qkv, unsigned int* cnt, unsigned int* list)
{
    int idx = blockIdx.x*256 + threadIdx.x;        // [0, 3*PLANE)
    int tsr = idx / PLANE;
    int rem = idx - tsr*PLANE;
    float* buf = qkv + (size_t)tsr*TENSOR_ELEMS;
    float v = 0.f; bool flag = false;
    #pragma unroll
    for (int t = 0; t < T_; ++t) {
        float x = buf[(size_t)t*PLANE + rem];
        float h = v + (x - v)*0.5f;
        bool s = h >= 1.0f;
        flag |= fabsf(h - 1.0f) < FLAG_TOL;
        buf[(size_t)t*PLANE + rem] = s ? 1.0f : 0.0f;
        v = s ? 0.0f : h;
    }
    if (flag) {
        unsigned int p = atomicAdd(cnt, 1u);
        if (p < MAXFLAG) list[p] = (unsigned int)idx;
    }
}

__global__ void fixup_qkv(const float* __restrict__ x,
                          const float* __restrict__ Wq, const float* __restrict__ Wk,
                          const float* __restrict__ Wv,
                          float* qkv, const unsigned int* cnt, const unsigned int* list)
{
    unsigned int n = *cnt; if (n > MAXFLAG) n = MAXFLAG;
    int lane = threadIdx.x;                        // 64 threads = 1 wave
    for (unsigned int ii = blockIdx.x; ii < n; ii += gridDim.x) {
        unsigned int id = list[ii];
        int tsr = id / PLANE;
        int rem = id - tsr*PLANE;
        int r = rem >> 9, e = rem & (D_-1);
        const float* W = (tsr==0) ? Wq : (tsr==1 ? Wk : Wv);
        float* buf = qkv + (size_t)tsr*TENSOR_ELEMS;
        double dots[T_];
        #pragma unroll
        for (int t = 0; t < T_; ++t) {
            const float* xr = x + (size_t)(t*BN_ + r)*D_;
            const float* wr = W + (size_t)e*D_;
            double p = 0.0;
            for (int d = lane; d < D_; d += 64)
                p += (double)xr[d] * (double)wr[d];
            #pragma unroll
            for (int off = 32; off > 0; off >>= 1)
                p += __shfl_down(p, off);
            dots[t] = p;
        }
        if (lane == 0) {
            double v = 0.0;
            #pragma unroll
            for (int t = 0; t < T_; ++t) {
                double h = v + (dots[t] - v)/2.0;
                bool s = h >= 1.0;
                buf[(size_t)t*PLANE + rem] = s ? 1.0f : 0.0f;
                v = s ? 0.0 : h;
            }
        }
    }
}

// ---------------------------------------------------------------------------
// MFMA attention (exact integer math in bf16/f32).
// ---------------------------------------------------------------------------
#define NP 208   // 13 * 16 (padded N)
#define QSTR 72  // LDS row stride (ushorts) for Q/K tiles
#define JP 224   // 7 * 32 (padded j for PV K-dim)
#define VSTR 232 // LDS row stride for Vt / S strips

__global__ __launch_bounds__(256)
void attn_qk(const float* __restrict__ qb, const float* __restrict__ kb,
             float* __restrict__ attn_out)
{
    __shared__ ushort Qs[NP][QSTR];
    __shared__ ushort Ks[NP][QSTR];
    int tb = blockIdx.x, h = blockIdx.y;
    int tid = threadIdx.x, wave = tid >> 6, lane = tid & 63;

    for (int idx = tid; idx < NP*16; idx += 256) {
        int j = idx >> 4, d4 = (idx & 15) << 2;
        ushort qv[4] = {0,0,0,0}, kv[4] = {0,0,0,0};
        if (j < N_) {
            size_t base = ((size_t)tb*N_ + j)*D_ + (size_t)h*DH + d4;
            float4 q4 = *(const float4*)(qb + base);
            float4 k4 = *(const float4*)(kb + base);
            qv[0] = q4.x!=0.f?0x3F80:0; qv[1] = q4.y!=0.f?0x3F80:0;
            qv[2] = q4.z!=0.f?0x3F80:0; qv[3] = q4.w!=0.f?0x3F80:0;
            kv[0] = k4.x!=0.f?0x3F80:0; kv[1] = k4.y!=0.f?0x3F80:0;
            kv[2] = k4.z!=0.f?0x3F80:0; kv[3] = k4.w!=0.f?0x3F80:0;
        }
        #pragma unroll
        for (int r = 0; r < 4; ++r) { Qs[j][d4+r] = qv[r]; Ks[j][d4+r] = kv[r]; }
    }
    __syncthreads();

    const int il = lane & 15;
    const int kk = (lane >> 4) << 3;
    const int ig = (lane >> 4) << 2;
    const size_t amap = ((size_t)tb*H_ + h)*(size_t)(N_*N_);

    for (int it = wave; it < 13; it += 4) {
        int i0 = it << 4;
        short8v a0 = *(const short8v*)&Qs[i0 + il][kk];
        short8v a1 = *(const short8v*)&Qs[i0 + il][kk + 32];
        for (int jt = 0; jt < 13; ++jt) {
            int j0 = jt << 4;
            short8v b0 = *(const short8v*)&Ks[j0 + il][kk];
            short8v b1 = *(const short8v*)&Ks[j0 + il][kk + 32];
            f32x4 c = {0.f, 0.f, 0.f, 0.f};
            c = __builtin_amdgcn_mfma_f32_16x16x32_bf16(a0, b0, c, 0, 0, 0);
            c = __builtin_amdgcn_mfma_f32_16x16x32_bf16(a1, b1, c, 0, 0, 0);
            int j = j0 + il;
            if (j < N_) {
                #pragma unroll
                for (int r = 0; r < 4; ++r) {
                    int i = i0 + ig + r;
                    if (i < N_) attn_out[amap + (size_t)i*N_ + j] = c[r]*0.125f;
                }
            }
        }
    }
}

// O = attn @ V. Writes O directly as bf16 hi/lo planes (EXACT: O = m/8, m<2^14).
__global__ __launch_bounds__(256)
void attn_pv(const float* __restrict__ attn, const float* __restrict__ vb,
             ushort* __restrict__ ohi, ushort* __restrict__ olo)
{
    __shared__ ushort Vt[DH][VSTR];
    __shared__ ushort Ss[4][16][VSTR];
    int tb = blockIdx.x, h = blockIdx.y;
    int tid = threadIdx.x, wave = tid >> 6, lane = tid & 63;

    for (int idx = tid; idx < JP*16; idx += 256) {
        int j = idx >> 4, d4 = (idx & 15) << 2;
        ushort vv[4] = {0,0,0,0};
        if (j < N_) {
            size_t base = ((size_t)tb*N_ + j)*D_ + (size_t)h*DH + d4;
            float4 v4 = *(const float4*)(vb + base);
            vv[0] = v4.x!=0.f?0x3F80:0; vv[1] = v4.y!=0.f?0x3F80:0;
            vv[2] = v4.z!=0.f?0x3F80:0; vv[3] = v4.w!=0.f?0x3F80:0;
        }
        Vt[d4+0][j]=vv[0]; Vt[d4+1][j]=vv[1]; Vt[d4+2][j]=vv[2]; Vt[d4+3][j]=vv[3];
    }
    for (int idx = lane; idx < 16*16; idx += 64)
        Ss[wave][idx >> 4][208 + (idx & 15)] = 0;
    __syncthreads();

    const int il = lane & 15, kk = (lane >> 4) << 3, ig = (lane >> 4) << 2;
    const size_t amap = ((size_t)tb*H_ + h)*(size_t)(N_*N_);

    for (int it = wave; it < 13; it += 4) {
        int i0 = it << 4;
        #pragma unroll 4
        for (int r = 0; r < 16; ++r) {
            int i = i0 + r;
            bool live = i < N_;
            const float* arow = attn + amap + (size_t)i*N_;
            for (int c = lane; c < NP; c += 64) {
                float av = (live && c < N_) ? arow[c] : 0.f;
                Ss[wave][r][c] = (ushort)(__float_as_uint(av) >> 16);
            }
        }
        #pragma unroll
        for (int dt = 0; dt < 4; ++dt) {
            f32x4 o = {0.f, 0.f, 0.f, 0.f};
            #pragma unroll
            for (int kt = 0; kt < 7; ++kt) {
                short8v a = *(const short8v*)&Ss[wave][il][kt*32 + kk];
                short8v b = *(const short8v*)&Vt[dt*16 + il][kt*32 + kk];
                o = __builtin_amdgcn_mfma_f32_16x16x32_bf16(a, b, o, 0, 0, 0);
            }
            #pragma unroll
            for (int r = 0; r < 4; ++r) {
                int i = i0 + ig + r;
                if (i < N_) {
                    size_t oidx = ((size_t)tb*N_ + i)*D_ + (size_t)h*DH + dt*16 + il;
                    float ov = o[r];
                    ushort hv = bf16_rne(ov);
                    float rem = ov - bf16_f(hv);
                    ohi[oidx] = hv;
                    olo[oidx] = bf16_rne(rem);
                }
            }
        }
    }
}

// ---------------------------------------------------------------------------
// Final LIF (proj -> output spikes) with flagging, and its f64 fixup.
// ---------------------------------------------------------------------------
__global__ void lif_proj(const float* __restrict__ proj, float* __restrict__ outp,
                         unsigned int* cnt, unsigned int* list)
{
    int idx = blockIdx.x*256 + threadIdx.x;        // [0, PLANE)
    float v = 0.f; bool flag = false;
    #pragma unroll
    for (int t = 0; t < T_; ++t) {
        float xv = proj[(size_t)t*PLANE + idx];
        float h = v + (xv - v)*0.5f;
        bool s = h >= 1.0f;
        flag |= fabsf(h - 1.0f) < FLAG_TOL;
        outp[(size_t)t*PLANE + idx] = s ? 1.0f : 0.0f;
        v = s ? 0.0f : h;
    }
    if (flag) {
        unsigned int p = atomicAdd(cnt, 1u);
        if (p < MAXFLAG) list[p] = (unsigned int)idx;
    }
}

// obuf reconstructed exactly from hi+lo planes (split is exact for O = m/8).
__global__ void fixup_proj(const ushort* __restrict__ ohi, const ushort* __restrict__ olo,
                           const float* __restrict__ Wp, const float* __restrict__ bp,
                           float* __restrict__ outp,
                           const unsigned int* cnt, const unsigned int* list)
{
    unsigned int n = *cnt; if (n > MAXFLAG) n = MAXFLAG;
    int lane = threadIdx.x;
    for (unsigned int ii = blockIdx.x; ii < n; ii += gridDim.x) {
        unsigned int rem = list[ii];
        int r = rem >> 9, e = rem & (D_-1);
        double dots[T_];
        #pragma unroll
        for (int t = 0; t < T_; ++t) {
            size_t abase = (size_t)(t*BN_ + r)*D_;
            const float* wr = Wp + (size_t)e*D_;
            double p = 0.0;
            for (int d = lane; d < D_; d += 64) {
                double a = (double)bf16_f(ohi[abase + d]) + (double)bf16_f(olo[abase + d]);
                p += a * (double)wr[d];
            }
            #pragma unroll
            for (int off = 32; off > 0; off >>= 1)
                p += __shfl_down(p, off);
            dots[t] = p;
        }
        if (lane == 0) {
            double v = 0.0;
            #pragma unroll
            for (int t = 0; t < T_; ++t) {
                double xt = dots[t] + (double)bp[e];
                double h = v + (xt - v)/2.0;
                bool s = h >= 1.0;
                outp[(size_t)t*PLANE + rem] = s ? 1.0f : 0.0f;
                v = s ? 0.0 : h;
            }
        }
    }
}

// ---------------------------------------------------------------------------
extern "C" void kernel_launch(void* const* d_in, const int* in_sizes, int n_in,
                              void* d_out, int out_size, void* d_ws, size_t ws_size,
                              hipStream_t stream)
{
    const float* x  = (const float*)d_in[0];
    const float* Wq = (const float*)d_in[1];
    const float* Wk = (const float*)d_in[2];
    const float* Wv = (const float*)d_in[3];
    const float* Wp = (const float*)d_in[4];
    const float* bp = (const float*)d_in[5];
    float* out_spk  = (float*)d_out;                       // (T,B,N,D) spikes
    float* attn_out = (float*)d_out + TENSOR_ELEMS;        // (T,B,H,N,N)

    char* ws = (char*)d_ws;
    const size_t BUFB = (size_t)TENSOR_ELEMS * sizeof(float);
    float* qkv  = (float*)ws;                              // R0..R2: q,k,v f32
    float* pbuf = qkv;                                     // proj out reuses R0
    // R3: x hi/lo splits; later obuf hi/lo (x dead after QKV GEMM)
    ushort* xhi = (ushort*)(ws + 3*BUFB);
    ushort* xlo = xhi + TENSOR_ELEMS;
    ushort* ohi = xhi;
    ushort* olo = xlo;
    // flag lists at tail
    unsigned int* cnt0  = (unsigned int*)(ws + 4*BUFB);
    unsigned int* cnt1  = cnt0 + 1;
    unsigned int* list0 = cnt0 + 2;
    unsigned int* list1 = list0 + MAXFLAG;
    if (ws_size < 4*BUFB + 8 + 2*(size_t)MAXFLAG*4) return;

    // QKV weight splits live in the attn_map region of d_out (free until attn_qk)
    ushort* w3hi = (ushort*)attn_out;
    ushort* w3lo = w3hi + 3*WELEMS;
    // Wp split lives in qkv[1] (dead after attn_qk)
    ushort* wphi = (ushort*)(ws + 1*BUFB);
    ushort* wplo = wphi + WELEMS;

    hipMemsetAsync(cnt0, 0, 8, stream);

    // input splits
    split_kernel<<<TENSOR_ELEMS/1024, 256, 0, stream>>>(x, xhi, xlo, TENSOR_ELEMS);
    split_kernel<<<WELEMS/1024, 256, 0, stream>>>(Wq, w3hi,            w3lo,            WELEMS);
    split_kernel<<<WELEMS/1024, 256, 0, stream>>>(Wk, w3hi +   WELEMS, w3lo +   WELEMS, WELEMS);
    split_kernel<<<WELEMS/1024, 256, 0, stream>>>(Wv, w3hi + 2*WELEMS, w3lo + 2*WELEMS, WELEMS);

    // QKV projections: fused, grid (99, 2, 3)
    gemm_split<<<dim3((M_ + GBM - 1)/GBM, D_/GBN, 3), 256, 0, stream>>>(
        xhi, xlo, w3hi, w3lo, nullptr, qkv, WELEMS, (long)TENSOR_ELEMS);

    // LIF + flags, exact f64 fixup
    lif3_flag<<<3*PLANE/256, 256, 0, stream>>>(qkv, cnt0, list0);
    fixup_qkv<<<1024, 64, 0, stream>>>(x, Wq, Wk, Wv, qkv, cnt0, list0);

    // attention (overwrites the w3 scratch in attn_out — safe after GEMM)
    attn_qk<<<dim3(T_*B_, H_), 256, 0, stream>>>(
        qkv, qkv + TENSOR_ELEMS, attn_out);
    // Wp split into qkv[1] (k spikes dead after attn_qk)
    split_kernel<<<WELEMS/1024, 256, 0, stream>>>(Wp, wphi, wplo, WELEMS);
    attn_pv<<<dim3(T_*B_, H_), 256, 0, stream>>>(
        attn_out, qkv + 2*(size_t)TENSOR_ELEMS, ohi, olo);

    // output projection + bias, LIF + flags, f64 fixup
    gemm_split<<<dim3((M_ + GBM - 1)/GBM, D_/GBN, 1), 256, 0, stream>>>(
        ohi, olo, wphi, wplo, bp, pbuf, 0, 0);
    lif_proj<<<PLANE/256, 256, 0, stream>>>(pbuf, out_spk, cnt1, list1);
    fixup_proj<<<1024, 64, 0, stream>>>(ohi, olo, Wp, bp, out_spk, cnt1, list1);
}

// Round 4
// 396.360 us; speedup vs baseline: 2.4982x; 1.0427x over previous
//
#include <hip/hip_runtime.h>
#include <stdint.h>

// Problem constants
#define T_ 4
#define B_ 16
#define N_ 197
#define D_ 512
#define H_ 8
#define DH 64
#define BN_ (B_*N_)              // 3152 rows per timestep
#define PLANE (BN_*D_)           // 1,613,824 elems per t-plane
#define M_ (T_*BN_)              // 12608 GEMM rows
#define TENSOR_ELEMS (T_*PLANE)  // 6,455,296 elems per (T,B,N,D) tensor
#define WELEMS (D_*D_)           // 262,144
#define MH (M_*H_)               // 100,864 bitmask words per tensor
#define FLAG_TOL 1e-3f           // ~200 sigma of split-GEMM dot error
#define MAXFLAG 65536

typedef __attribute__((ext_vector_type(8))) short short8v;
typedef __attribute__((ext_vector_type(4))) float f32x4;
typedef __attribute__((ext_vector_type(16))) float f32x16;
typedef __attribute__((ext_vector_type(4))) unsigned short ushort4v;
typedef unsigned long long u64;

__device__ __forceinline__ ushort bf16_rne(float v) {
    uint u = __float_as_uint(v);
    return (ushort)((u + 0x7FFFu + ((u >> 16) & 1u)) >> 16);
}
__device__ __forceinline__ float bf16_f(ushort h) {
    return __uint_as_float(((uint)h) << 16);
}

// async global->LDS 16B copy (one per lane)
__device__ __forceinline__ void gload16(const void* g, void* l) {
    __builtin_amdgcn_global_load_lds(
        (const __attribute__((address_space(1))) unsigned int*)g,
        (__attribute__((address_space(3))) unsigned int*)l, 16, 0, 0);
}

// ---------------------------------------------------------------------------
// f32 -> bf16 hi/lo split (a = hi + lo + O(2^-18 a))
// ---------------------------------------------------------------------------
__global__ void split_kernel(const float* __restrict__ src, ushort* __restrict__ hi,
                             ushort* __restrict__ lo, int n)
{
    int i = (blockIdx.x*256 + threadIdx.x)*4;
    if (i >= n) return;
    float4 v = *(const float4*)(src + i);
    ushort4v hv, lv;
    float f[4] = {v.x, v.y, v.z, v.w};
    #pragma unroll
    for (int j = 0; j < 4; ++j) {
        ushort h = bf16_rne(f[j]);
        float rem = f[j] - bf16_f(h);
        hv[j] = h;
        lv[j] = bf16_rne(rem);
    }
    *(ushort4v*)(hi + i) = hv;
    *(ushort4v*)(lo + i) = lv;
}

// ---------------------------------------------------------------------------
// 3-pass split-bf16 MFMA GEMM: C[M,512] = A[M,512] @ W[512,512]^T (+bias)
// 128x128 tile, BK=32, 4 waves x (64x64), mfma_f32_32x32x16_bf16.
// LDS: 4 planes (Ah,Al,Bh,Bl) in chunk-planar layout [c][row][8 ushorts]
// -> conflict-free ds_read_b128 AND linear global_load_lds dest.
// 1D grid, yz-fastest decode + bijective XCD swizzle (A-strip L2 locality).
// ---------------------------------------------------------------------------
__global__ __launch_bounds__(256, 3)
void gemm_split(const ushort* __restrict__ Ahi, const ushort* __restrict__ Alo,
                const ushort* __restrict__ Whi, const ushort* __restrict__ Wlo,
                const float* __restrict__ bias, float* __restrict__ C,
                int wplane, long cplane, int nyz, int nz)
{
    __shared__ ushort smem[16384];   // 4 x [4][128][8] = 32 KB
    const int tid = threadIdx.x;
    const int wave = tid >> 6, lane = tid & 63;
    const int wm = wave >> 1, wn = wave & 1;
    const int l31 = lane & 31, lg = lane >> 5;

    // bijective XCD swizzle (m204), then yz-fastest decode
    int nwg = gridDim.x, orig = blockIdx.x;
    int q8 = nwg >> 3, r8 = nwg & 7, xcd = orig & 7, loc = orig >> 3;
    int wg = (xcd < r8 ? xcd*(q8+1) : r8*(q8+1) + (xcd-r8)*q8) + loc;
    int bx = wg / nyz, yz = wg - bx*nyz;
    int by = yz / nz,  z  = yz - by*nz;

    const int bm0 = bx * 128, bn0 = by * 128;
    const ushort* Wh = Whi + (size_t)z * wplane;
    const ushort* Wl = Wlo + (size_t)z * wplane;
    float* Cz = C + (size_t)z * cplane;

    f32x16 acc[2][2];
    #pragma unroll
    for (int fi = 0; fi < 2; ++fi)
        #pragma unroll
        for (int fj = 0; fj < 2; ++fj)
            #pragma unroll
            for (int r = 0; r < 16; ++r) acc[fi][fj][r] = 0.f;

    for (int kt = 0; kt < D_; kt += 32) {
        // stage A/B hi/lo tiles: 8 x 16B chunks per thread, direct to LDS
        #pragma unroll
        for (int i = 0; i < 8; ++i) {
            const int p = i >> 1;                 // 0:Ah 1:Al 2:Bh 3:Bl
            const int q = ((i & 1) << 8) | tid;   // chunk id in plane [0,512)
            const int c = q >> 7, row = q & 127;
            ushort* dst = smem + p*4096 + q*8;
            if (p < 2) {
                int gr = bm0 + row;
                if (gr < M_) {
                    const ushort* src = (p == 0 ? Ahi : Alo) + (size_t)gr*D_ + kt + c*8;
                    gload16(src, dst);
                }
            } else {
                int gc = bn0 + row;
                const ushort* src = (p == 2 ? Wh : Wl) + (size_t)gc*D_ + kt + c*8;
                gload16(src, dst);
            }
        }
        __syncthreads();                          // vmcnt drain + barrier
        #pragma unroll
        for (int s = 0; s < 2; ++s) {
            const int c = (s << 1) | lg;          // = (s*16 + lg*8)/8
            short8v ah[2], al[2], bh[2], bl[2];
            #pragma unroll
            for (int f = 0; f < 2; ++f) {
                int ra = wm*64 + f*32 + l31;
                int rb = wn*64 + f*32 + l31;
                ah[f] = *(const short8v*)&smem[        (c*128 + ra)*8];
                al[f] = *(const short8v*)&smem[ 4096 + (c*128 + ra)*8];
                bh[f] = *(const short8v*)&smem[ 8192 + (c*128 + rb)*8];
                bl[f] = *(const short8v*)&smem[12288 + (c*128 + rb)*8];
            }
            #pragma unroll
            for (int fi = 0; fi < 2; ++fi)
                #pragma unroll
                for (int fj = 0; fj < 2; ++fj) {
                    acc[fi][fj] = __builtin_amdgcn_mfma_f32_32x32x16_bf16(ah[fi], bh[fj], acc[fi][fj], 0, 0, 0);
                    acc[fi][fj] = __builtin_amdgcn_mfma_f32_32x32x16_bf16(ah[fi], bl[fj], acc[fi][fj], 0, 0, 0);
                    acc[fi][fj] = __builtin_amdgcn_mfma_f32_32x32x16_bf16(al[fi], bh[fj], acc[fi][fj], 0, 0, 0);
                }
        }
        __syncthreads();                          // protect LDS overwrite
    }
    // epilogue: C/D layout col=lane&31, row=(reg&3)+8*(reg>>2)+4*(lane>>5)
    #pragma unroll
    for (int fi = 0; fi < 2; ++fi)
        #pragma unroll
        for (int fj = 0; fj < 2; ++fj) {
            int gcol = bn0 + wn*64 + fj*32 + l31;
            float bv = bias ? bias[gcol] : 0.f;
            #pragma unroll
            for (int r = 0; r < 16; ++r) {
                int grow = bm0 + wm*64 + fi*32 + (r&3) + 8*(r>>2) + 4*lg;
                if (grow < M_)
                    Cz[(size_t)grow*D_ + gcol] = acc[fi][fj][r] + bv;
            }
        }
}

// ---------------------------------------------------------------------------
// LIF over T=4 for q,k,v -> packed 64-bit spike masks (bit d of word (t,b,n,h)).
// Flags near-threshold chains for f64 fixup.
// ---------------------------------------------------------------------------
__global__ void lif3_bits(const float* __restrict__ qkv, u64* __restrict__ bits3,
                          unsigned int* cnt, unsigned int* list)
{
    int idx = blockIdx.x*256 + threadIdx.x;        // [0, 3*PLANE)
    int tsr = idx / PLANE;
    int rem = idx - tsr*PLANE;
    const float* buf = qkv + (size_t)tsr*TENSOR_ELEMS;
    u64* bits = bits3 + (size_t)tsr*MH;
    int r = rem >> 9, h = (rem >> 6) & 7;          // wave-uniform
    int lane = threadIdx.x & 63;                   // = d
    float v = 0.f; bool flag = false;
    #pragma unroll
    for (int t = 0; t < T_; ++t) {
        float x = buf[(size_t)t*PLANE + rem];
        float hh = v + (x - v)*0.5f;
        bool s = hh >= 1.0f;
        flag |= fabsf(hh - 1.0f) < FLAG_TOL;
        u64 m = __ballot(s);
        if (lane == 0) bits[(size_t)(t*BN_ + r)*H_ + h] = m;
        v = s ? 0.0f : hh;
    }
    if (flag) {
        unsigned int p = atomicAdd(cnt, 1u);
        if (p < MAXFLAG) list[p] = (unsigned int)idx;
    }
}

// f64 exact recompute of flagged chains; corrects single bits in the masks.
__global__ void fixup_qkv(const float* __restrict__ x,
                          const float* __restrict__ Wq, const float* __restrict__ Wk,
                          const float* __restrict__ Wv,
                          u64* __restrict__ bits3,
                          const unsigned int* cnt, const unsigned int* list)
{
    unsigned int n = *cnt; if (n > MAXFLAG) n = MAXFLAG;
    int lane = threadIdx.x;                        // 64 threads = 1 wave
    for (unsigned int ii = blockIdx.x; ii < n; ii += gridDim.x) {
        unsigned int id = list[ii];
        int tsr = id / PLANE;
        int rem = id - tsr*PLANE;
        int r = rem >> 9, e = rem & (D_-1);
        const float* W = (tsr==0) ? Wq : (tsr==1 ? Wk : Wv);
        u64* bits = bits3 + (size_t)tsr*MH;
        double dots[T_];
        #pragma unroll
        for (int t = 0; t < T_; ++t) {
            const float* xr = x + (size_t)(t*BN_ + r)*D_;
            const float* wr = W + (size_t)e*D_;
            double p = 0.0;
            for (int d = lane; d < D_; d += 64)
                p += (double)xr[d] * (double)wr[d];
            #pragma unroll
            for (int off = 32; off > 0; off >>= 1)
                p += __shfl_down(p, off);
            dots[t] = p;
        }
        if (lane == 0) {
            double v = 0.0;
            u64 bit = 1ull << (e & 63);
            #pragma unroll
            for (int t = 0; t < T_; ++t) {
                double hh = v + (dots[t] - v)/2.0;
                bool s = hh >= 1.0;
                size_t w = (size_t)(t*BN_ + r)*H_ + (e >> 6);
                if (s) atomicOr(&bits[w], bit);
                else   atomicAnd(&bits[w], ~bit);
                v = s ? 0.0 : hh;
            }
        }
    }
}

// ---------------------------------------------------------------------------
// MFMA attention from packed spike masks (exact integer math).
// ---------------------------------------------------------------------------
#define NP 208   // 13 * 16 (padded N)
#define QSTR 72  // LDS row stride (ushorts) for Q/K tiles
#define JP 224   // 7 * 32 (padded j for PV K-dim)
#define VSTR 232 // LDS row stride for Vt / S strips

__global__ __launch_bounds__(256)
void attn_qk(const u64* __restrict__ qbits, const u64* __restrict__ kbits,
             float* __restrict__ attn_out)
{
    __shared__ ushort Qs[NP][QSTR];
    __shared__ ushort Ks[NP][QSTR];
    int tb = blockIdx.x, h = blockIdx.y;
    int tid = threadIdx.x, wave = tid >> 6, lane = tid & 63;

    for (int idx = tid; idx < NP*16; idx += 256) {
        int j = idx >> 4, d4 = (idx & 15) << 2;
        ushort qv[4] = {0,0,0,0}, kv[4] = {0,0,0,0};
        if (j < N_) {
            size_t w = ((size_t)tb*N_ + j)*H_ + h;
            u64 qw = qbits[w], kw = kbits[w];
            #pragma unroll
            for (int r = 0; r < 4; ++r) {
                qv[r] = ((qw >> (d4+r)) & 1ull) ? 0x3F80 : 0;
                kv[r] = ((kw >> (d4+r)) & 1ull) ? 0x3F80 : 0;
            }
        }
        #pragma unroll
        for (int r = 0; r < 4; ++r) { Qs[j][d4+r] = qv[r]; Ks[j][d4+r] = kv[r]; }
    }
    __syncthreads();

    const int il = lane & 15;
    const int kk = (lane >> 4) << 3;
    const int ig = (lane >> 4) << 2;
    const size_t amap = ((size_t)tb*H_ + h)*(size_t)(N_*N_);

    for (int it = wave; it < 13; it += 4) {
        int i0 = it << 4;
        short8v a0 = *(const short8v*)&Qs[i0 + il][kk];
        short8v a1 = *(const short8v*)&Qs[i0 + il][kk + 32];
        for (int jt = 0; jt < 13; ++jt) {
            int j0 = jt << 4;
            short8v b0 = *(const short8v*)&Ks[j0 + il][kk];
            short8v b1 = *(const short8v*)&Ks[j0 + il][kk + 32];
            f32x4 c = {0.f, 0.f, 0.f, 0.f};
            c = __builtin_amdgcn_mfma_f32_16x16x32_bf16(a0, b0, c, 0, 0, 0);
            c = __builtin_amdgcn_mfma_f32_16x16x32_bf16(a1, b1, c, 0, 0, 0);
            int j = j0 + il;
            if (j < N_) {
                #pragma unroll
                for (int r = 0; r < 4; ++r) {
                    int i = i0 + ig + r;
                    if (i < N_) attn_out[amap + (size_t)i*N_ + j] = c[r]*0.125f;
                }
            }
        }
    }
}

// O = attn @ V. Writes O as bf16 hi/lo planes (EXACT: O = m/8, m < 2^14).
__global__ __launch_bounds__(256)
void attn_pv(const float* __restrict__ attn, const u64* __restrict__ vbits,
             ushort* __restrict__ ohi, ushort* __restrict__ olo)
{
    __shared__ ushort Vt[DH][VSTR];
    __shared__ ushort Ss[4][16][VSTR];
    int tb = blockIdx.x, h = blockIdx.y;
    int tid = threadIdx.x, wave = tid >> 6, lane = tid & 63;

    for (int idx = tid; idx < JP*16; idx += 256) {
        int j = idx >> 4, d4 = (idx & 15) << 2;
        ushort vv[4] = {0,0,0,0};
        if (j < N_) {
            u64 vw = vbits[((size_t)tb*N_ + j)*H_ + h];
            #pragma unroll
            for (int r = 0; r < 4; ++r)
                vv[r] = ((vw >> (d4+r)) & 1ull) ? 0x3F80 : 0;
        }
        Vt[d4+0][j]=vv[0]; Vt[d4+1][j]=vv[1]; Vt[d4+2][j]=vv[2]; Vt[d4+3][j]=vv[3];
    }
    for (int idx = lane; idx < 16*16; idx += 64)
        Ss[wave][idx >> 4][208 + (idx & 15)] = 0;
    __syncthreads();

    const int il = lane & 15, kk = (lane >> 4) << 3, ig = (lane >> 4) << 2;
    const size_t amap = ((size_t)tb*H_ + h)*(size_t)(N_*N_);

    for (int it = wave; it < 13; it += 4) {
        int i0 = it << 4;
        #pragma unroll 4
        for (int r = 0; r < 16; ++r) {
            int i = i0 + r;
            bool live = i < N_;
            const float* arow = attn + amap + (size_t)i*N_;
            for (int c = lane; c < NP; c += 64) {
                float av = (live && c < N_) ? arow[c] : 0.f;
                Ss[wave][r][c] = (ushort)(__float_as_uint(av) >> 16);
            }
        }
        #pragma unroll
        for (int dt = 0; dt < 4; ++dt) {
            f32x4 o = {0.f, 0.f, 0.f, 0.f};
            #pragma unroll
            for (int kt = 0; kt < 7; ++kt) {
                short8v a = *(const short8v*)&Ss[wave][il][kt*32 + kk];
                short8v b = *(const short8v*)&Vt[dt*16 + il][kt*32 + kk];
                o = __builtin_amdgcn_mfma_f32_16x16x32_bf16(a, b, o, 0, 0, 0);
            }
            #pragma unroll
            for (int r = 0; r < 4; ++r) {
                int i = i0 + ig + r;
                if (i < N_) {
                    size_t oidx = ((size_t)tb*N_ + i)*D_ + (size_t)h*DH + dt*16 + il;
                    float ov = o[r];
                    ushort hv = bf16_rne(ov);
                    float rem = ov - bf16_f(hv);
                    ohi[oidx] = hv;
                    olo[oidx] = bf16_rne(rem);
                }
            }
        }
    }
}

// ---------------------------------------------------------------------------
// Final LIF (proj -> output spikes f32) with flagging, and its f64 fixup.
// ---------------------------------------------------------------------------
__global__ void lif_proj(const float* __restrict__ proj, float* __restrict__ outp,
                         unsigned int* cnt, unsigned int* list)
{
    int idx = blockIdx.x*256 + threadIdx.x;        // [0, PLANE)
    float v = 0.f; bool flag = false;
    #pragma unroll
    for (int t = 0; t < T_; ++t) {
        float xv = proj[(size_t)t*PLANE + idx];
        float h = v + (xv - v)*0.5f;
        bool s = h >= 1.0f;
        flag |= fabsf(h - 1.0f) < FLAG_TOL;
        outp[(size_t)t*PLANE + idx] = s ? 1.0f : 0.0f;
        v = s ? 0.0f : h;
    }
    if (flag) {
        unsigned int p = atomicAdd(cnt, 1u);
        if (p < MAXFLAG) list[p] = (unsigned int)idx;
    }
}

__global__ void fixup_proj(const ushort* __restrict__ ohi, const ushort* __restrict__ olo,
                           const float* __restrict__ Wp, const float* __restrict__ bp,
                           float* __restrict__ outp,
                           const unsigned int* cnt, const unsigned int* list)
{
    unsigned int n = *cnt; if (n > MAXFLAG) n = MAXFLAG;
    int lane = threadIdx.x;
    for (unsigned int ii = blockIdx.x; ii < n; ii += gridDim.x) {
        unsigned int rem = list[ii];
        int r = rem >> 9, e = rem & (D_-1);
        double dots[T_];
        #pragma unroll
        for (int t = 0; t < T_; ++t) {
            size_t abase = (size_t)(t*BN_ + r)*D_;
            const float* wr = Wp + (size_t)e*D_;
            double p = 0.0;
            for (int d = lane; d < D_; d += 64) {
                double a = (double)bf16_f(ohi[abase + d]) + (double)bf16_f(olo[abase + d]);
                p += a * (double)wr[d];
            }
            #pragma unroll
            for (int off = 32; off > 0; off >>= 1)
                p += __shfl_down(p, off);
            dots[t] = p;
        }
        if (lane == 0) {
            double v = 0.0;
            #pragma unroll
            for (int t = 0; t < T_; ++t) {
                double xt = dots[t] + (double)bp[e];
                double h = v + (xt - v)/2.0;
                bool s = h >= 1.0;
                outp[(size_t)t*PLANE + rem] = s ? 1.0f : 0.0f;
                v = s ? 0.0 : h;
            }
        }
    }
}

// ---------------------------------------------------------------------------
extern "C" void kernel_launch(void* const* d_in, const int* in_sizes, int n_in,
                              void* d_out, int out_size, void* d_ws, size_t ws_size,
                              hipStream_t stream)
{
    const float* x  = (const float*)d_in[0];
    const float* Wq = (const float*)d_in[1];
    const float* Wk = (const float*)d_in[2];
    const float* Wv = (const float*)d_in[3];
    const float* Wp = (const float*)d_in[4];
    const float* bp = (const float*)d_in[5];
    float* out_spk  = (float*)d_out;                       // (T,B,N,D) spikes
    float* attn_out = (float*)d_out + TENSOR_ELEMS;        // (T,B,H,N,N)

    char* ws = (char*)d_ws;
    const size_t BUFB = (size_t)TENSOR_ELEMS * sizeof(float);
    // R0: q f32 -> pbuf (proj out)
    float* qkv  = (float*)ws;
    float* pbuf = qkv;
    // R1: k f32 -> ohi ; R2: v f32 -> olo
    ushort* ohi = (ushort*)(ws + 1*BUFB);
    ushort* olo = (ushort*)(ws + 2*BUFB);
    // R3: x hi/lo splits -> (after QKV GEMM) spike bitmasks + Wp split
    ushort* xhi = (ushort*)(ws + 3*BUFB);
    ushort* xlo = xhi + TENSOR_ELEMS;
    u64* bits3  = (u64*)(ws + 3*BUFB);                     // q,k,v masks (2.42 MB)
    u64* qbits  = bits3;
    u64* kbits  = bits3 + MH;
    u64* vbits  = bits3 + 2*(size_t)MH;
    ushort* wphi = (ushort*)(ws + 3*BUFB + (4u<<20));      // Wp split (1 MB)
    ushort* wplo = wphi + WELEMS;
    // flag lists at tail
    unsigned int* cnt0  = (unsigned int*)(ws + 4*BUFB);
    unsigned int* cnt1  = cnt0 + 1;
    unsigned int* list0 = cnt0 + 2;
    unsigned int* list1 = list0 + MAXFLAG;
    if (ws_size < 4*BUFB + 8 + 2*(size_t)MAXFLAG*4) return;

    // QKV weight splits live in the attn_map region of d_out (free until attn_qk)
    ushort* w3hi = (ushort*)attn_out;
    ushort* w3lo = w3hi + 3*WELEMS;

    hipMemsetAsync(cnt0, 0, 8, stream);

    // input splits
    split_kernel<<<TENSOR_ELEMS/1024, 256, 0, stream>>>(x, xhi, xlo, TENSOR_ELEMS);
    split_kernel<<<WELEMS/1024, 256, 0, stream>>>(Wq, w3hi,            w3lo,            WELEMS);
    split_kernel<<<WELEMS/1024, 256, 0, stream>>>(Wk, w3hi +   WELEMS, w3lo +   WELEMS, WELEMS);
    split_kernel<<<WELEMS/1024, 256, 0, stream>>>(Wv, w3hi + 2*WELEMS, w3lo + 2*WELEMS, WELEMS);

    // QKV projections: 1D grid, x-tiles x (y=4 col-blocks x z=3 weights)
    gemm_split<<<99*12, 256, 0, stream>>>(
        xhi, xlo, w3hi, w3lo, nullptr, qkv, WELEMS, (long)TENSOR_ELEMS, 12, 3);

    // LIF -> packed spike masks (overwrites dead xhi region) + flags, f64 fixup
    lif3_bits<<<3*PLANE/256, 256, 0, stream>>>(qkv, bits3, cnt0, list0);
    fixup_qkv<<<1024, 64, 0, stream>>>(x, Wq, Wk, Wv, bits3, cnt0, list0);
    // Wp split (R3 tail; k f32 still needed? no - only bits are used downstream)
    split_kernel<<<WELEMS/1024, 256, 0, stream>>>(Wp, wphi, wplo, WELEMS);

    // attention (attn_qk overwrites the w3 scratch in attn_out - safe after GEMM)
    attn_qk<<<dim3(T_*B_, H_), 256, 0, stream>>>(qbits, kbits, attn_out);
    attn_pv<<<dim3(T_*B_, H_), 256, 0, stream>>>(attn_out, vbits, ohi, olo);

    // output projection + bias, LIF + flags, f64 fixup
    gemm_split<<<99*4, 256, 0, stream>>>(
        ohi, olo, wphi, wplo, bp, pbuf, 0, 0, 4, 1);
    lif_proj<<<PLANE/256, 256, 0, stream>>>(pbuf, out_spk, cnt1, list1);
    fixup_proj<<<1024, 64, 0, stream>>>(ohi, olo, Wp, bp, out_spk, cnt1, list1);
}